// Round 1
// 142.611 us; speedup vs baseline: 1.0703x; 1.0703x over previous
//
#include <hip/hip_runtime.h>
#include <stdint.h>
#include <stddef.h>

#define NROWS 8192
#define DIM   1024
#define RB    512      // fp4 bytes per row (DIM/2)
#define TEMP  10.0f

#define BM 256
#define BN 256
#define BK 128         // K elements per tile; 64 bytes fp4 per row
#define NT (DIM / BK)  // 8 K-tiles

typedef __attribute__((ext_vector_type(8))) int i32x8;
typedef __attribute__((ext_vector_type(16))) float floatx16;

#define FENCE() asm volatile("" ::: "memory")
#define BARRIER() do { FENCE(); __builtin_amdgcn_s_barrier(); FENCE(); } while (0)

// async 16B global->LDS (global_load_lds_dwordx4); LDS dest is wave-uniform
// base + lane*16 -- all staging dests are slot*16 by construction.
__device__ __forceinline__ void load16_lds(const unsigned char* g, unsigned char* l) {
    __builtin_amdgcn_global_load_lds(
        (__attribute__((address_space(1))) void*)(g),
        (__attribute__((address_space(3))) void*)(l),
        16, 0, 0);
}

// fp4 e2m1 quantize of x (already in grid units, sigma~1): nearest of
// {0,.5,1,1.5,2,3,4,6} with sign. 7-threshold chain, branch-free.
__device__ __forceinline__ unsigned fp4q(float x) {
    float a = fabsf(x);
    a = fminf(a, 6.0f);
    unsigned c = (unsigned)(a >= 0.25f) + (unsigned)(a >= 0.75f)
               + (unsigned)(a >= 1.25f) + (unsigned)(a >= 1.75f)
               + (unsigned)(a >= 2.5f)  + (unsigned)(a >= 3.5f)
               + (unsigned)(a >= 5.0f);
    return c | ((__float_as_uint(x) >> 28) & 8u);
}

// fp4 operand: data in regs 0..3 (cbsz/blgp=4 reads 4 regs), upper zeroed.
__device__ __forceinline__ i32x8 op8(int4 lo) {
    union { i32x8 v; int4 q[2]; } u;
    u.q[0] = lo;
    u.q[1] = make_int4(0, 0, 0, 0);
    return u.v;
}

// ---------------------------------------------------------------------------
// Quantized layout (per matrix, 4 MB) -- MFMA-fragment-linear:
//   element e of row r: chunk c = e>>5 (16B = 32 fp4), it = c>>2,
//   ks = (c>>1)&1, fh = c&1
//   byte = it*524288 + (r>>5)*2048 + ks*1024 + fh*512 + (r&31)*16
// => a (blockM, it) A-tile is 16 KB CONTIGUOUS at it*524288 + blockM*16384,
//    already ordered so slot s = rgLocal*128 + ks*64 + lane (lane = fh*32+fr).
//    Staging = straight contiguous copy (coalesced global, linear LDS dest);
//    fragment read = ds_read_b128 at (base + lane*16) + imm, conflict-free.
// ---------------------------------------------------------------------------

// Wave-per-row L2 normalize + quantize to fp4 e2m1 at fixed scale 2^-5
// (values x32 -> sigma ~1 grid unit). Same numerics as before; only the
// store addresses changed (fragment-linear layout, via LDS transpose).
__global__ __launch_bounds__(256) void normalize_kernel(
    const float* __restrict__ img, const float* __restrict__ txt,
    unsigned char* __restrict__ imgq, unsigned char* __restrict__ txtq,
    float* __restrict__ out)
{
    __shared__ __align__(16) unsigned short sc[4][256];   // [wave][c*64+lane]
    const int t = threadIdx.x;
    const int lane = t & 63, wave = t >> 6;
    const int gw = blockIdx.x * 4 + wave;                 // row id, 0..16383
    const float* src = (gw < NROWS) ? img + (size_t)gw * DIM
                                    : txt + (size_t)(gw - NROWS) * DIM;
    float4 v[4];
    float ss = 0.f;
#pragma unroll
    for (int c = 0; c < 4; c++) {
        v[c] = ((const float4*)src)[lane + 64 * c];
        ss += v[c].x * v[c].x + v[c].y * v[c].y + v[c].z * v[c].z + v[c].w * v[c].w;
    }
#pragma unroll
    for (int off = 32; off; off >>= 1) ss += __shfl_xor(ss, off);
    const float scale = 32.0f / fmaxf(sqrtf(ss), 1e-12f);   // x32 = fp4 grid
#pragma unroll
    for (int c = 0; c < 4; c++) {
        unsigned p = fp4q(v[c].x * scale)
                   | (fp4q(v[c].y * scale) << 4)
                   | (fp4q(v[c].z * scale) << 8)
                   | (fp4q(v[c].w * scale) << 12);
        sc[wave][c * 64 + lane] = (unsigned short)p;   // ushort u covers elems [4u,4u+4)
    }
    __syncthreads();
    // 128 store units: (rr = row in block 0..3, k = chunk 0..31). Chunk k =
    // ushorts [8k..8k+8) of row rr. 4 consecutive t share (it,ks,fh) and write
    // 4 consecutive fr*16 slots -> 64B-line coalesced.
    if (t < 128) {
        const int rr = t & 3, k = t >> 2;
        const int gr0 = blockIdx.x * 4;      // block never straddles img/txt (4 | 8192)
        unsigned char* dq = (gr0 < NROWS) ? imgq : txtq;
        const int r = (gr0 < NROWS ? gr0 : gr0 - NROWS) + rr;
        const int4 d = *(const int4*)&sc[rr][k * 8];
        const int it = k >> 2, ks = (k >> 1) & 1, fh = k & 1;
        *(int4*)(dq + (size_t)it * 524288 + (size_t)((r >> 5) * 2048
                 + ks * 1024 + fh * 512 + (r & 31) * 16)) = d;
    }
    if (gw == 0 && lane == 0) out[0] = 0.f;   // zero the atomic target
}

// 256x256 tile NT-GEMM on fp4 e2m1 via MX-scaled MFMA 32x32x64 (cbsz=blgp=4,
// unit scales; sims come out x1024, folded into epilogue constants).
//
// Schedule (T3+T4+T5, m201-style): 3-stage LDS (96 KB), 2 phases per K-tile
// (one per ks). Phase = { 6 ds_read_b128 (this ks's frags) ; 2 global_load_lds
// for tile it+2 ; [vmcnt once per tile] ; barrier ; setprio1 ; 8 MFMA ;
// setprio0 ; barrier }. Raw s_barrier (no implicit drain); the only vmcnt in
// steady state is vmcnt(4) -- drains tile it+1's 4 loads, leaves tile it+2's
// 4 in flight across barriers. FIFO check: outstanding at (it,ks1) =
// {it+1:4 old, it+2:4 new}; vmcnt(4) completes the oldest 4 = it+1. Tail:
// it=NT-2 has only tile NT-1's 4 outstanding -> vmcnt(0) there.
// WAR safety: DMA to buffer (it+2)%3 == (it-1)%3 issues after (it-1,ks1)'s
// trailing barrier; that phase's ds_reads drained before its MFMAs (data dep)
// which precede the barrier.
__global__ __launch_bounds__(512, 2) void simloss_kernel(
    const unsigned char* __restrict__ An,   // img fp4, fragment-linear
    const unsigned char* __restrict__ Bn,   // txt fp4, fragment-linear
    const float* __restrict__ bias,
    float* __restrict__ out)
{
    __shared__ __align__(16) unsigned char smem[3 * 32768];  // 3x (A 16K + B 16K)
    __shared__ float red[24];

    const int t = threadIdx.x;
    const int lane = t & 63;
    const int wave = t >> 6;

    // XCD-aware swizzle: xcd = bid&7; per XCD, N sweeps {x, x+8, x+16, x+24}
    const int bid = blockIdx.x;
    const int blockN = (bid & 7) + 8 * ((bid >> 3) & 3);   // 0..31
    const int blockM = bid >> 5;                            // 0..31

    const unsigned char* gA = An + blockM * 16384 + t * 16;
    const unsigned char* gB = Bn + blockN * 16384 + t * 16;

    // wave tile: 2x4 waves, each 128x64 (mi 0..3, ni 0..1 of 32x32 tiles)
    const int waveM = (wave >> 2) * 128;
    const int waveN = (wave & 3) * 64;
    const int rgA = (wave >> 2) * 4;    // A rowgroup base within tile (8 total)
    const int cgB = (wave & 3) * 2;     // B colgroup base within tile (8 total)
    const int fr = lane & 31;
    const int fh = lane >> 5;

    floatx16 acc[4][2];
#pragma unroll
    for (int mi = 0; mi < 4; mi++)
#pragma unroll
        for (int ni = 0; ni < 2; ni++)
            acc[mi][ni] = (floatx16)(0.f);

    // prologue: tiles 0 (buf 0) and 1 (buf 1); keep tile 1 in flight.
    load16_lds(gA, smem + t * 16);
    load16_lds(gA + 8192, smem + t * 16 + 8192);
    load16_lds(gB, smem + 16384 + t * 16);
    load16_lds(gB + 8192, smem + 16384 + t * 16 + 8192);
    load16_lds(gA + 524288, smem + 32768 + t * 16);
    load16_lds(gA + 524288 + 8192, smem + 32768 + t * 16 + 8192);
    load16_lds(gB + 524288, smem + 32768 + 16384 + t * 16);
    load16_lds(gB + 524288 + 8192, smem + 32768 + 16384 + t * 16 + 8192);
    asm volatile("s_waitcnt vmcnt(4)" ::: "memory");
    BARRIER();

#pragma unroll
    for (int it = 0; it < NT; ++it) {
        const int buf = it % 3;
        const int pbuf = (it + 2) % 3;
        const unsigned char* Lw = smem + buf * 32768 + lane * 16;
#pragma unroll
        for (int ks = 0; ks < 2; ++ks) {
            // fragment reads for THIS phase's MFMAs: one shared vaddr,
            // compile-time immediates (max 16384+7*2048+1024 < 64K).
            int4 aF[4], bF[2];
#pragma unroll
            for (int mi = 0; mi < 4; mi++)
                aF[mi] = *(const int4*)(Lw + (rgA + mi) * 2048 + ks * 1024);
#pragma unroll
            for (int ni = 0; ni < 2; ni++)
                bF[ni] = *(const int4*)(Lw + 16384 + (cgB + ni) * 2048 + ks * 1024);

            // stage half of tile it+2 (A-half in ks0, B-half in ks1)
            if (it < NT - 2) {
                const size_t ko = (size_t)(it + 2) * 524288;
                unsigned char* Ld = smem + pbuf * 32768 + t * 16;
                if (ks == 0) {
                    load16_lds(gA + ko, Ld);
                    load16_lds(gA + ko + 8192, Ld + 8192);
                } else {
                    load16_lds(gB + ko, Ld + 16384);
                    load16_lds(gB + ko + 8192, Ld + 24576);
                }
            }
            // counted vmcnt once per K-tile: tile it+1 must be resident
            // before next iteration's reads; tile it+2's 4 stay in flight.
            if (ks == 1) {
                if (it < NT - 2) {
                    asm volatile("s_waitcnt vmcnt(4)" ::: "memory");
                } else if (it == NT - 2) {
                    asm volatile("s_waitcnt vmcnt(0)" ::: "memory");
                }
            }
            BARRIER();

            i32x8 a8[4], b8[2];
#pragma unroll
            for (int mi = 0; mi < 4; mi++) a8[mi] = op8(aF[mi]);
#pragma unroll
            for (int ni = 0; ni < 2; ni++) b8[ni] = op8(bF[ni]);

            asm volatile("s_setprio 1");
#pragma unroll
            for (int mi = 0; mi < 4; mi++)
#pragma unroll
                for (int ni = 0; ni < 2; ni++)
                    acc[mi][ni] = __builtin_amdgcn_mfma_scale_f32_32x32x64_f8f6f4(
                        a8[mi], b8[ni], acc[mi][ni],
                        4, 4,                 // cbsz=FP4(e2m1), blgp=FP4(e2m1)
                        0, 0x7f7f7f7f,        // opsel_a, scale_a = 2^0
                        0, 0x7f7f7f7f);       // opsel_b, scale_b = 2^0
            asm volatile("s_setprio 0");
            BARRIER();
        }
    }

    // Branch-free epilogue. Raw acc = 1024*sim (both operands x32).
    // logit = -10*sim + b, x = label*logit.
    //   softplus(x) = (x+|x|)/2 + log(1+e^-|x|)
    //   sum(x)/2 = sum_diag(logit) - sum_all(logit)/2   (linear!)
    // log2 domain: w = logit*log2e; sum softplus =
    //   ln2 * sum(log2(1+2^-|w|) + |w|/2) + sum(x)/2.
    const float bv = bias[0];
    const float c1 = -TEMP * 1.4426950408889634f / 1024.0f;  // on raw acc
    const float c0 = bv * 1.4426950408889634f;
    float accP = 0.f, accQ = 0.f, accD = 0.f;
    // C/D map (32x32, verified): col = lane&31 (=j/txt), row = (reg&3) +
    // 8*(reg>>2) + 4*(lane>>5) (=i/img); final scalar transpose-invariant.
    const int gi0 = blockM * BM + waveM + 4 * fh;
    const int gj0 = blockN * BN + waveN + fr;
#pragma unroll
    for (int mi = 0; mi < 4; mi++) {
#pragma unroll
        for (int ni = 0; ni < 2; ni++) {
#pragma unroll
            for (int reg = 0; reg < 16; reg++) {
                float s = acc[mi][ni][reg];          // raw = 1024*sim
                float w = fmaf(s, c1, c0);
                float e2 = __builtin_amdgcn_exp2f(-fabsf(w));
                accP += __builtin_amdgcn_logf(1.0f + e2);   // v_log = log2
                accP = fmaf(0.5f, fabsf(w), accP);
                accQ += s;
            }
        }
    }
    // diagonal sims: only the 32 blocks with blockM == blockN have any
    const bool diagblk = (blockN == blockM);
    if (diagblk) {
#pragma unroll
        for (int mi = 0; mi < 4; mi++)
#pragma unroll
            for (int ni = 0; ni < 2; ni++)
#pragma unroll
                for (int reg = 0; reg < 16; reg++) {
                    int ig = gi0 + mi * 32 + (reg & 3) + 8 * (reg >> 2);
                    int jg = gj0 + ni * 32;
                    if (ig == jg) accD += acc[mi][ni][reg];
                }
    }
#pragma unroll
    for (int off = 32; off; off >>= 1) {
        accP += __shfl_xor(accP, off);
        accQ += __shfl_xor(accQ, off);
        accD += __shfl_xor(accD, off);
    }
    if (lane == 0) {
        red[wave * 3 + 0] = accP;
        red[wave * 3 + 1] = accQ;
        red[wave * 3 + 2] = accD;
    }
    __syncthreads();
    if (t == 0) {
        float P = 0.f, Q = 0.f, D = 0.f;
#pragma unroll
        for (int w = 0; w < 8; w++) {
            P += red[w * 3 + 0];
            Q += red[w * 3 + 1];
            D += red[w * 3 + 2];
        }
        Q *= (1.0f / 1024.0f);   // raw -> true sim sums
        D *= (1.0f / 1024.0f);
        // sum softplus over this block's 256x256 sims:
        //   ln2*P + [5*Q - 32768*b]  (+ diag part: -10*D + 256*b)
        float contrib = fmaf(0.6931471805599453f, P, fmaf(5.0f, Q, -32768.0f * bv));
        if (diagblk) contrib += fmaf(-TEMP, D, 256.0f * bv);
        atomicAdd(out, contrib * (1.0f / 8192.0f));
    }
}

extern "C" void kernel_launch(void* const* d_in, const int* in_sizes, int n_in,
                              void* d_out, int out_size, void* d_ws, size_t ws_size,
                              hipStream_t stream) {
    const float* txt = (const float*)d_in[0];   // text_embeddings [8192][1024]
    const float* img = (const float*)d_in[1];   // image_embeddings [8192][1024]
    const float* bias = (const float*)d_in[2];  // [1]
    float* out = (float*)d_out;

    unsigned char* imgq = (unsigned char*)d_ws;                      // 4 MB fp4
    unsigned char* txtq = imgq + (size_t)NROWS * RB;                 // 4 MB fp4

    normalize_kernel<<<dim3(2 * NROWS / 4), dim3(256), 0, stream>>>(
        img, txt, imgq, txtq, out);

    simloss_kernel<<<dim3((NROWS / BM) * (NROWS / BN)), dim3(512), 0, stream>>>(
        imgq, txtq, bias, out);
}